// Round 3
// baseline (426.011 us; speedup 1.0000x reference)
//
#include <hip/hip_runtime.h>
#include <hip/hip_bf16.h>

typedef unsigned short u16;
typedef __attribute__((ext_vector_type(8))) short short8;
typedef __attribute__((ext_vector_type(4))) float f32x4;

#define B_ 8
#define V_ 64
#define T_ 256
#define T1_ 257
#define D_ 256
#define H_ 8
#define DH_ 32

__device__ __forceinline__ u16 f2bf(float f){
  union { float f; unsigned int u; } v; v.f = f;
  unsigned int u = v.u;
  return (u16)((u + 0x7fffu + ((u >> 16) & 1u)) >> 16);
}

// ---------------- kernel 1: LN stats + masked xn partial-sums + weight conv ----------------
// grid (B*V, 4), block 256 = 4 waves. One WAVE per t. Also converts wqkv(V)/wproj
// to bf16 (64 elems per block). Partial xn-sums stored per (bv,y) — no atomics.
__global__ void k1_ln(const float* __restrict__ x, const int* __restrict__ mask,
                      const float* __restrict__ lnw, const float* __restrict__ lnb,
                      const float* __restrict__ wqkv, const float* __restrict__ wproj,
                      float* __restrict__ musig, float* __restrict__ xsump,
                      u16* __restrict__ wv, u16* __restrict__ wp){
  int bv = blockIdx.x;
  int y = blockIdx.y;
  int tid = threadIdx.x;
  int lane = tid & 63, wid = tid >> 6;
  // folded weight conversion: 2048 blocks x 64 elems = 131072
  if (tid < 64){
    int i = (y * 512 + bv) * 64 + tid;
    if (i < 65536) wv[i] = f2bf(wqkv[131072 + i]);
    else           wp[i - 65536] = f2bf(wproj[i - 65536]);
  }
  int t0 = y * 65;
  int tend = t0 + 65; if (tend > T1_) tend = T1_;
  __shared__ float xsred[4][D_];
  float4 w4 = *(const float4*)&lnw[lane * 4];
  float4 b4 = *(const float4*)&lnb[lane * 4];
  float xs0 = 0.f, xs1 = 0.f, xs2 = 0.f, xs3 = 0.f;
  for (int t = t0 + wid; t < tend; t += 4){
    float4 v = *(const float4*)&x[((long)bv * T1_ + t) * D_ + lane * 4];
    float s  = v.x + v.y + v.z + v.w;
    float s2 = v.x*v.x + v.y*v.y + v.z*v.z + v.w*v.w;
    #pragma unroll
    for (int off = 1; off < 64; off <<= 1){
      s  += __shfl_xor(s,  off, 64);
      s2 += __shfl_xor(s2, off, 64);
    }
    float mu   = s * (1.f / 256.f);
    float var  = s2 * (1.f / 256.f) - mu * mu;
    float rstd = rsqrtf(var + 1e-5f);
    if (lane == 0){
      musig[((long)bv * T1_ + t) * 2]     = mu;
      musig[((long)bv * T1_ + t) * 2 + 1] = rstd;
    }
    int m = (t == 0) ? 1 : mask[bv * T_ + (t - 1)];
    if (m){
      xs0 += (v.x - mu) * rstd * w4.x + b4.x;
      xs1 += (v.y - mu) * rstd * w4.y + b4.y;
      xs2 += (v.z - mu) * rstd * w4.z + b4.z;
      xs3 += (v.w - mu) * rstd * w4.w + b4.w;
    }
  }
  xsred[wid][lane * 4]     = xs0;
  xsred[wid][lane * 4 + 1] = xs1;
  xsred[wid][lane * 4 + 2] = xs2;
  xsred[wid][lane * 4 + 3] = xs3;
  __syncthreads();
  float r = xsred[0][tid] + xsred[1][tid] + xsred[2][tid] + xsred[3][tid];
  xsump[((long)bv * 4 + y) * D_ + tid] = r;
}

// ---------------- kernel 2a: q,k projections (tiny) ----------------
// grid (512, 4), block 256 = 4 waves. Wave (y*4+wid) computes 16 outputs.
__global__ void k2a_qk(const float* __restrict__ x, const int* __restrict__ mask,
                       const float* __restrict__ lnw, const float* __restrict__ lnb,
                       const float* __restrict__ wqkv,
                       const float* __restrict__ musig, const float* __restrict__ xsump,
                       float* __restrict__ qout, float* __restrict__ kout){
  int bv = blockIdx.x, tid = threadIdx.x;
  int lane = tid & 63, wid = tid >> 6;
  __shared__ __align__(16) float xn0[D_];
  __shared__ __align__(16) float xs[D_];
  __shared__ float redc[4];
  int s = mask[bv * T_ + tid];
  #pragma unroll
  for (int off = 32; off >= 1; off >>= 1) s += __shfl_down(s, off, 64);
  if (lane == 0) redc[wid] = (float)s;
  __syncthreads();
  float cnt = 1.f + redc[0] + redc[1] + redc[2] + redc[3];
  float mu = musig[((long)bv * T1_) * 2], rstd = musig[((long)bv * T1_) * 2 + 1];
  xn0[tid] = (x[((long)bv * T1_) * D_ + tid] - mu) * rstd * lnw[tid] + lnb[tid];
  float ps = xsump[((long)bv * 4) * D_ + tid] + xsump[((long)bv * 4 + 1) * D_ + tid]
           + xsump[((long)bv * 4 + 2) * D_ + tid] + xsump[((long)bv * 4 + 3) * D_ + tid];
  xs[tid] = ps * (1.f / cnt);
  __syncthreads();
  float4 xq = *(const float4*)&xn0[lane * 4];
  float4 xk = *(const float4*)&xs[lane * 4];
  int e0 = (blockIdx.y * 4 + wid) * 16;
  for (int i = 0; i < 16; ++i){
    int e = e0 + i;
    float4 wq4 = *(const float4*)&wqkv[(long)e * D_ + lane * 4];
    float4 wk4 = *(const float4*)&wqkv[(long)(256 + e) * D_ + lane * 4];
    float sq = xq.x*wq4.x + xq.y*wq4.y + xq.z*wq4.z + xq.w*wq4.w;
    float sk = xk.x*wk4.x + xk.y*wk4.y + xk.z*wk4.z + xk.w*wk4.w;
    #pragma unroll
    for (int off = 32; off >= 1; off >>= 1){
      sq += __shfl_down(sq, off, 64);
      sk += __shfl_down(sk, off, 64);
    }
    if (lane == 0){ qout[bv * D_ + e] = sq; kout[bv * D_ + e] = sk; }
  }
}

// ---------------- kernel 2b: 64x64 attention per (b,h) ----------------
__global__ void k2b_attn(const float* __restrict__ q, const float* __restrict__ k,
                         u16* __restrict__ attn){
  int bh = blockIdx.x; int b = bh >> 3, h = bh & 7;
  int tid = threadIdx.x;  // q row
  __shared__ float qs[64][DH_], ks[64][DH_];
  for (int d = 0; d < DH_; ++d){
    qs[tid][d] = q[((long)(b * V_ + tid)) * D_ + h * DH_ + d];
    ks[tid][d] = k[((long)(b * V_ + tid)) * D_ + h * DH_ + d];
  }
  __syncthreads();
  const float scale = 0.17677669529663687f;  // 1/sqrt(32)
  float sc[64];
  float mx = -1e30f;
  #pragma unroll
  for (int j = 0; j < 64; ++j){
    float a = 0.f;
    #pragma unroll
    for (int d = 0; d < DH_; ++d) a += qs[tid][d] * ks[j][d];
    a *= scale; sc[j] = a; mx = fmaxf(mx, a);
  }
  float sum = 0.f;
  #pragma unroll
  for (int j = 0; j < 64; ++j){ float e = __expf(sc[j] - mx); sc[j] = e; sum += e; }
  float inv = 1.f / sum;
  #pragma unroll
  for (int j = 0; j < 64; ++j) attn[((long)bh * 64 + tid) * 64 + j] = f2bf(sc[j] * inv);
}

// ---------------- kernel 3: fused LN -> V-proj -> attn-mix -> out-proj -> residual ----------------
// grid B*T1 (2056), block 512 (8 waves). ONE shared buffer (36.9 KB) time-shared
// by Xs (stride 264), VT (stride 72), Ms (stride 264): VT write->read is
// intra-wave (wave w's mix head h=w reads exactly the cols wave w computed).
// ~37.5 KB LDS -> 4 blocks/CU = 32 waves/CU.
__global__ __launch_bounds__(512, 8) void k3_main(
    const float* __restrict__ x, const float* __restrict__ lnw, const float* __restrict__ lnb,
    const float* __restrict__ bproj, const float* __restrict__ musig,
    const u16* __restrict__ wv, const u16* __restrict__ wp,
    const u16* __restrict__ attn, float* __restrict__ out){
  constexpr int XS = 264;   // Xs/Ms row stride (u16): 132 dw = 4 mod 32 -> conflict-free b128
  constexpr int VS = 72;    // VT row stride (u16): 36 dw = 4 mod 32 -> conflict-free b128
  __shared__ __align__(16) u16 buf[256 * VS];   // 36,864 B
  __shared__ float ms_s[V_ * 2];

  int bt = blockIdx.x; int b = bt / T1_, t = bt % T1_;
  int tid = threadIdx.x;
  int w = tid >> 6, lane = tid & 63, lm = lane & 15, lq = lane >> 4;
  int cw = w * 32;   // this wave's output-column base

  if (tid < 128)
    ms_s[tid] = musig[(((long)b * V_ + (tid >> 1)) * T1_ + t) * 2 + (tid & 1)];
  // per-thread channel group is invariant across staging iters: keep ln params in regs
  int c8 = (tid & 31) * 8;
  float4 lw0 = *(const float4*)&lnw[c8];
  float4 lw1 = *(const float4*)&lnw[c8 + 4];
  float4 lb0 = *(const float4*)&lnb[c8];
  float4 lb1 = *(const float4*)&lnb[c8 + 4];
  __syncthreads();

  // ---- stage x slice with LN applied, as bf16, into Xs ----
  #pragma unroll
  for (int i = 0; i < 4; ++i){
    int vr = (i * 512 + tid) >> 5;
    const float* gp = x + (((long)b * V_ + vr) * T1_ + t) * D_ + c8;
    float4 a0 = *(const float4*)gp;
    float4 a1 = *(const float4*)(gp + 4);
    float mu = ms_s[vr * 2], rs = ms_s[vr * 2 + 1];
    union { u16 us[8]; uint4 q; } pk;
    pk.us[0] = f2bf((a0.x - mu) * rs * lw0.x + lb0.x);
    pk.us[1] = f2bf((a0.y - mu) * rs * lw0.y + lb0.y);
    pk.us[2] = f2bf((a0.z - mu) * rs * lw0.z + lb0.z);
    pk.us[3] = f2bf((a0.w - mu) * rs * lw0.w + lb0.w);
    pk.us[4] = f2bf((a1.x - mu) * rs * lw1.x + lb1.x);
    pk.us[5] = f2bf((a1.y - mu) * rs * lw1.y + lb1.y);
    pk.us[6] = f2bf((a1.z - mu) * rs * lw1.z + lb1.z);
    pk.us[7] = f2bf((a1.w - mu) * rs * lw1.w + lb1.w);
    *(uint4*)&buf[vr * XS + c8] = pk.q;
  }
  __syncthreads();

  // ---- GEMM1: vf = Xs(64x256) @ Wv^T ; wave w -> cols [32w,32w+32) ----
  f32x4 acc1[4][2];
  #pragma unroll
  for (int mt = 0; mt < 4; ++mt)
    #pragma unroll
    for (int nt = 0; nt < 2; ++nt) acc1[mt][nt] = (f32x4){0.f, 0.f, 0.f, 0.f};
  for (int kk = 0; kk < 8; ++kk){
    short8 af[4], bfr[2];
    #pragma unroll
    for (int mt = 0; mt < 4; ++mt)
      af[mt] = *(const short8*)&buf[(mt * 16 + lm) * XS + kk * 32 + lq * 8];
    #pragma unroll
    for (int nt = 0; nt < 2; ++nt)
      bfr[nt] = *(const short8*)&wv[(long)(cw + nt * 16 + lm) * D_ + kk * 32 + lq * 8];
    #pragma unroll
    for (int mt = 0; mt < 4; ++mt)
      #pragma unroll
      for (int nt = 0; nt < 2; ++nt)
        acc1[mt][nt] = __builtin_amdgcn_mfma_f32_16x16x32_bf16(af[mt], bfr[nt], acc1[mt][nt], 0, 0, 0);
  }
  __syncthreads();   // everyone done READING Xs; buf may be overwritten as VT

  // ---- VT write (own cols only; intra-wave consumer) ----
  #pragma unroll
  for (int mt = 0; mt < 4; ++mt)
    #pragma unroll
    for (int nt = 0; nt < 2; ++nt){
      int col = cw + nt * 16 + lm;
      int row = mt * 16 + lq * 4;
      union { u16 us[4]; uint2 q; } pv;
      #pragma unroll
      for (int r = 0; r < 4; ++r) pv.us[r] = f2bf(acc1[mt][nt][r]);
      *(uint2*)&buf[col * VS + row] = pv.q;
    }

  // ---- mix: head h=w: mix[q,c] = attn_h(64x64) @ vf[:,c], c in [32w,32w+32) ----
  int h = w;
  f32x4 acc2[4][2];
  #pragma unroll
  for (int mt = 0; mt < 4; ++mt)
    #pragma unroll
    for (int nt = 0; nt < 2; ++nt) acc2[mt][nt] = (f32x4){0.f, 0.f, 0.f, 0.f};
  #pragma unroll
  for (int kk = 0; kk < 2; ++kk){
    short8 af[4], bfr[2];
    #pragma unroll
    for (int mt = 0; mt < 4; ++mt)
      af[mt] = *(const short8*)&attn[((long)(b * H_ + h) * 64 + mt * 16 + lm) * 64 + kk * 32 + lq * 8];
    #pragma unroll
    for (int nt = 0; nt < 2; ++nt)
      bfr[nt] = *(const short8*)&buf[(cw + nt * 16 + lm) * VS + kk * 32 + lq * 8];
    #pragma unroll
    for (int mt = 0; mt < 4; ++mt)
      #pragma unroll
      for (int nt = 0; nt < 2; ++nt)
        acc2[mt][nt] = __builtin_amdgcn_mfma_f32_16x16x32_bf16(af[mt], bfr[nt], acc2[mt][nt], 0, 0, 0);
  }
  __syncthreads();   // everyone done READING VT; buf may be overwritten as Ms

  // ---- Ms write: row-major [var][channel]; wave w writes cols [32w,32w+32) ----
  #pragma unroll
  for (int mt = 0; mt < 4; ++mt)
    #pragma unroll
    for (int nt = 0; nt < 2; ++nt){
      int col = cw + nt * 16 + lm;
      #pragma unroll
      for (int r = 0; r < 4; ++r){
        int row = mt * 16 + lq * 4 + r;
        buf[row * XS + col] = f2bf(acc2[mt][nt][r]);
      }
    }
  __syncthreads();

  // ---- GEMM3: out = Ms(64x256) @ Wproj^T ----
  f32x4 acc3[4][2];
  #pragma unroll
  for (int mt = 0; mt < 4; ++mt)
    #pragma unroll
    for (int nt = 0; nt < 2; ++nt) acc3[mt][nt] = (f32x4){0.f, 0.f, 0.f, 0.f};
  for (int kk = 0; kk < 8; ++kk){
    short8 af[4], bfr[2];
    #pragma unroll
    for (int mt = 0; mt < 4; ++mt)
      af[mt] = *(const short8*)&buf[(mt * 16 + lm) * XS + kk * 32 + lq * 8];
    #pragma unroll
    for (int nt = 0; nt < 2; ++nt)
      bfr[nt] = *(const short8*)&wp[(long)(cw + nt * 16 + lm) * D_ + kk * 32 + lq * 8];
    #pragma unroll
    for (int mt = 0; mt < 4; ++mt)
      #pragma unroll
      for (int nt = 0; nt < 2; ++nt)
        acc3[mt][nt] = __builtin_amdgcn_mfma_f32_16x16x32_bf16(af[mt], bfr[nt], acc3[mt][nt], 0, 0, 0);
  }
  // ---- epilogue: + b_proj + x, store fp32 ----
  float bpa = bproj[cw + lm];
  float bpb = bproj[cw + 16 + lm];
  #pragma unroll
  for (int mt = 0; mt < 4; ++mt)
    #pragma unroll
    for (int nt = 0; nt < 2; ++nt){
      int e = cw + nt * 16 + lm;
      float bp = nt ? bpb : bpa;
      #pragma unroll
      for (int r = 0; r < 4; ++r){
        int vr = mt * 16 + lq * 4 + r;
        long g = (((long)b * V_ + vr) * T1_ + t) * D_ + e;
        out[g] = acc3[mt][nt][r] + bp + x[g];
      }
    }
}

// ---------------- launch ----------------
extern "C" void kernel_launch(void* const* d_in, const int* in_sizes, int n_in,
                              void* d_out, int out_size, void* d_ws, size_t ws_size,
                              hipStream_t stream){
  const float* x     = (const float*)d_in[0];
  const int*   mask  = (const int*)d_in[1];
  const float* lnw   = (const float*)d_in[2];
  const float* lnb   = (const float*)d_in[3];
  const float* wqkv  = (const float*)d_in[4];
  const float* wproj = (const float*)d_in[5];
  const float* bproj = (const float*)d_in[6];
  float* out = (float*)d_out;
  char* ws = (char*)d_ws;
  float* musig = (float*)(ws);              // 263168 f  -> 1,052,672 B
  float* xsump = (float*)(ws + 1052672);    // 512*4*256 f -> 2,097,152 B
  float* qbuf  = (float*)(ws + 3149824);    // 131072 f
  float* kbuf  = (float*)(ws + 3674112);    // 131072 f
  u16*   attn  = (u16*)  (ws + 4198400);    // 262144 u16
  u16*   wv    = (u16*)  (ws + 4722688);    // 65536 u16
  u16*   wp    = (u16*)  (ws + 4853760);    // 65536 u16

  k1_ln<<<dim3(512, 4), 256, 0, stream>>>(x, mask, lnw, lnb, wqkv, wproj, musig, xsump, wv, wp);
  k2a_qk<<<dim3(512, 4), 256, 0, stream>>>(x, mask, lnw, lnb, wqkv, musig, xsump, qbuf, kbuf);
  k2b_attn<<<64, 64, 0, stream>>>(qbuf, kbuf, attn);
  k3_main<<<B_ * T1_, 512, 0, stream>>>(x, lnw, lnb, bproj, musig, wv, wp, attn, out);
}